// Round 5
// baseline (1080.087 us; speedup 1.0000x reference)
//
#include <hip/hip_runtime.h>
#include <hip/hip_bf16.h>
#include <math.h>

#define NN 50000
#define FF 256
#define HH 64
#define LL 8
#define EE 1600000
#define CC 40

#define NCH 4
#define CHS 12500            // src chunk size
#define VN (NCH * NN)        // virtual rows = 200000
#define NBK ((VN + 127) / 128)  // 1563 buckets

using short8 = __attribute__((ext_vector_type(8))) short;
using f32x4  = __attribute__((ext_vector_type(4))) float;

// ---------------- chunked CSR build ----------------

__global__ void k_hist4(const int* __restrict__ src, const int* __restrict__ dst,
                        int* __restrict__ cnt) {
    int e = blockIdx.x * 256 + threadIdx.x;
    if (e < EE) {
        unsigned c = (unsigned)src[e] / CHS;
        atomicAdd(&cnt[c * NN + dst[e]], 1);
    }
}

__global__ void k_scanA(const int* __restrict__ cnt, int* __restrict__ incl, int* __restrict__ bsum) {
    __shared__ int buf[1024];
    int i = blockIdx.x * 1024 + threadIdx.x;
    int v = (i < VN) ? cnt[i] : 0;
    buf[threadIdx.x] = v;
    __syncthreads();
    for (int off = 1; off < 1024; off <<= 1) {
        int t = (threadIdx.x >= off) ? buf[threadIdx.x - off] : 0;
        __syncthreads();
        buf[threadIdx.x] += t;
        __syncthreads();
    }
    if (i < VN) incl[i] = buf[threadIdx.x];
    if (threadIdx.x == 1023) bsum[blockIdx.x] = buf[1023];
}

// exclusive scan of 196 block sums, one 1024-thread block
__global__ void k_scanB2(int* __restrict__ bsum) {
    __shared__ int buf[1024];
    int t = threadIdx.x;
    int v = (t < 196) ? bsum[t] : 0;
    int vin = v;
    buf[t] = v;
    __syncthreads();
    for (int off = 1; off < 1024; off <<= 1) {
        int u = (t >= off) ? buf[t - off] : 0;
        __syncthreads();
        buf[t] += u;
        __syncthreads();
    }
    if (t < 196) bsum[t] = buf[t] - vin;  // exclusive
}

__global__ void k_scanC(const int* __restrict__ cnt, const int* __restrict__ incl,
                        const int* __restrict__ bsum, int* __restrict__ row4) {
    int i = blockIdx.x * 1024 + threadIdx.x;
    if (i < VN) row4[i] = incl[i] - cnt[i] + bsum[blockIdx.x];
    if (i == 0) row4[VN] = EE;
}

__global__ void k_binit(const int* __restrict__ row4, int* __restrict__ bcur) {
    int t = blockIdx.x * 256 + threadIdx.x;
    if (t < NBK) bcur[t] = row4[t * 128];
}

// pass A: scatter into dense bucket frontiers
__global__ void k_scatA(const int* __restrict__ src, const int* __restrict__ dst,
                        const float* __restrict__ w, int* __restrict__ bcur,
                        int2* __restrict__ payA) {
    int e = blockIdx.x * 256 + threadIdx.x;
    if (e < EE) {
        int s = src[e];
        int d = dst[e];
        unsigned c = (unsigned)s / CHS;
        int vr = c * NN + d;
        int b = vr >> 7;
        int pos = atomicAdd(&bcur[b], 1);
        payA[pos] = make_int2(s | ((vr & 127) << 16), __float_as_int(w[e]));
    }
}

// pass B: per-bucket local scatter (L2-hot region, LDS cursors)
__global__ void k_scatB(const int* __restrict__ row4, const int2* __restrict__ payA,
                        int2* __restrict__ payB) {
    __shared__ int lcur[128];
    int b = blockIdx.x;
    int vr0 = b * 128;
    int vend = min(vr0 + 128, VN);
    int base = row4[vr0];
    int end = row4[vend];
    int t = threadIdx.x;
    if (t < 128 && vr0 + t < vend) lcur[t] = row4[vr0 + t] - base;
    __syncthreads();
    for (int i = base + t; i < end; i += 256) {
        int2 pk = payA[i];
        int dl = pk.x >> 16;  // 7 bits
        int p = atomicAdd(&lcur[dl], 1);
        payB[base + p] = make_int2(pk.x & 0xFFFF, pk.y);
    }
}

// ---------------- initial projection via MFMA: h0 = relu(x @ W0 + b0) ----------------
__global__ __launch_bounds__(512) void k_h0m(const float* __restrict__ x,
                                             const float* __restrict__ W0,
                                             const float* __restrict__ b0,
                                             float* __restrict__ h0) {
    __shared__ __align__(16) __hip_bfloat16 ax[256][72];
    __shared__ __align__(16) __hip_bfloat16 bw[64][72];

    int tid = threadIdx.x;
    int lane = tid & 63;
    int w = tid >> 6;
    int nbase = blockIdx.x * 256;

    f32x4 acc[2][4];
#pragma unroll
    for (int nf = 0; nf < 2; ++nf)
#pragma unroll
        for (int cf = 0; cf < 4; ++cf) acc[nf][cf] = (f32x4){0.f, 0.f, 0.f, 0.f};

    int arow = w * 32 + (lane & 15);
    int kq = (lane >> 4) * 8;

    for (int kc = 0; kc < 4; ++kc) {
        __syncthreads();
#pragma unroll
        for (int p = 0; p < 8; ++p) {
            int q = p * 512 + tid;
            int r = q >> 4, cq = q & 15;
            int node = nbase + r;
            float4 v = {0.f, 0.f, 0.f, 0.f};
            if (node < NN) v = *(const float4*)&x[(size_t)node * FF + kc * 64 + cq * 4];
            __hip_bfloat16* d = &ax[r][cq * 4];
            d[0] = __float2bfloat16(v.x);
            d[1] = __float2bfloat16(v.y);
            d[2] = __float2bfloat16(v.z);
            d[3] = __float2bfloat16(v.w);
        }
#pragma unroll
        for (int u = 0; u < 8; ++u) {
            int k = (tid >> 6) * 8 + u;
            float v = W0[(size_t)(kc * 64 + k) * HH + lane];
            bw[lane][k] = __float2bfloat16(v);
        }
        __syncthreads();
#pragma unroll
        for (int ks = 0; ks < 2; ++ks) {
            short8 a0 = *(const short8*)&ax[arow][ks * 32 + kq];
            short8 a1 = *(const short8*)&ax[arow + 16][ks * 32 + kq];
#pragma unroll
            for (int cf = 0; cf < 4; ++cf) {
                short8 b = *(const short8*)&bw[cf * 16 + (lane & 15)][ks * 32 + kq];
                acc[0][cf] = __builtin_amdgcn_mfma_f32_16x16x32_bf16(a0, b, acc[0][cf], 0, 0, 0);
                acc[1][cf] = __builtin_amdgcn_mfma_f32_16x16x32_bf16(a1, b, acc[1][cf], 0, 0, 0);
            }
        }
    }

#pragma unroll
    for (int nf = 0; nf < 2; ++nf) {
#pragma unroll
        for (int cf = 0; cf < 4; ++cf) {
            int c = cf * 16 + (lane & 15);
            float bias = b0[c];
#pragma unroll
            for (int r = 0; r < 4; ++r) {
                int node = nbase + w * 32 + nf * 16 + ((lane >> 4) << 2) + r;
                if (node < NN) h0[(size_t)node * HH + c] = fmaxf(acc[nf][cf][r] + bias, 0.f);
            }
        }
    }
}

// ---------------- fused layer: chunked SpMM + blend + matvec + relu ----------------
// one wave per 4 dst nodes; lane = feature channel. Chunk loop OUTER so all
// resident waves gather from the same ~3.2MB src slice (per-XCD L2 resident).
__global__ void k_layer(const float* __restrict__ hin, const float* __restrict__ h0,
                        const int* __restrict__ row4, const int2* __restrict__ payB,
                        const float* __restrict__ Wl, float beta, float* __restrict__ hout) {
    int lane = threadIdx.x & 63;
    int n0 = (blockIdx.x * 4 + (threadIdx.x >> 6)) * 4;

    float acc[4] = {0.f, 0.f, 0.f, 0.f};
    for (int c = 0; c < NCH; ++c) {
#pragma unroll
        for (int u = 0; u < 4; ++u) {
            int vr = c * NN + n0 + u;
            int rb = row4[vr], re = row4[vr + 1];
            float a = acc[u];
            for (int base = rb; base < re; base += 64) {
                int idx = base + lane;
                int2 pv = make_int2(0, 0);
                if (idx < re) pv = payB[idx];
                int ecnt = min(64, re - base);
                int k = 0;
                for (; k + 16 <= ecnt; k += 16) {
                    float vv[16], ws[16];
#pragma unroll
                    for (int t = 0; t < 16; t++) {
                        int ss = __builtin_amdgcn_readlane(pv.x, k + t);
                        ws[t] = __int_as_float(__builtin_amdgcn_readlane(pv.y, k + t));
                        vv[t] = hin[(size_t)ss * HH + lane];
                    }
#pragma unroll
                    for (int t = 0; t < 16; t++) a = fmaf(ws[t], vv[t], a);
                }
                if (k + 8 <= ecnt) {
                    float vv[8], ws[8];
#pragma unroll
                    for (int t = 0; t < 8; t++) {
                        int ss = __builtin_amdgcn_readlane(pv.x, k + t);
                        ws[t] = __int_as_float(__builtin_amdgcn_readlane(pv.y, k + t));
                        vv[t] = hin[(size_t)ss * HH + lane];
                    }
#pragma unroll
                    for (int t = 0; t < 8; t++) a = fmaf(ws[t], vv[t], a);
                    k += 8;
                }
                for (; k < ecnt; k++) {
                    int ss = __builtin_amdgcn_readlane(pv.x, k);
                    float ww = __int_as_float(__builtin_amdgcn_readlane(pv.y, k));
                    a = fmaf(ww, hin[(size_t)ss * HH + lane], a);
                }
            }
            acc[u] = a;
        }
    }

    float hmix[4];
#pragma unroll
    for (int u = 0; u < 4; ++u)
        hmix[u] = fmaf(0.9f, acc[u], 0.1f * h0[(size_t)(n0 + u) * HH + lane]);

    int hb[4];
#pragma unroll
    for (int u = 0; u < 4; ++u) hb[u] = __float_as_int(hmix[u]);
    float a2[4] = {0.f, 0.f, 0.f, 0.f};
#pragma unroll
    for (int j = 0; j < HH; j++) {
        float wr = Wl[j * HH + lane];
#pragma unroll
        for (int u = 0; u < 4; ++u) {
            float hj = __int_as_float(__builtin_amdgcn_readlane(hb[u], j));
            a2[u] = fmaf(hj, wr, a2[u]);
        }
    }
#pragma unroll
    for (int u = 0; u < 4; ++u) {
        float outv = (1.f - beta) * hmix[u] + beta * a2[u];
        hout[(size_t)(n0 + u) * HH + lane] = fmaxf(outv, 0.f);
    }
}

// ---------------- head via MFMA ----------------
__global__ __launch_bounds__(512) void k_head(const float* __restrict__ h,
                                              const float* __restrict__ W2,
                                              const float* __restrict__ b2,
                                              float* __restrict__ out) {
    __shared__ __align__(16) __hip_bfloat16 hb[256][72];
    __shared__ float hf[256][65];
    __shared__ __align__(16) __hip_bfloat16 Bc[8][48][72];

    int tid = threadIdx.x;
    int lane = tid & 63;
    int w = tid >> 6;
    int nbase = blockIdx.x * 256;

#pragma unroll
    for (int p = 0; p < 32; ++p) {
        int idx = p * 512 + tid;
        int r = idx >> 6, c = idx & 63;
        int node = nbase + r;
        float v = (node < NN) ? h[(size_t)node * HH + c] : 0.f;
        hf[r][c] = v;
        hb[r][c] = __float2bfloat16(v);
    }
    for (int p = tid; p < 8 * 8 * 64; p += 512) {
        int il = p >> 9;
        int c = 40 + ((p >> 6) & 7);
        int j = p & 63;
        Bc[il][c][j] = __float2bfloat16(0.f);
    }

    f32x4 acc[2][3];
#pragma unroll
    for (int nf = 0; nf < 2; ++nf)
#pragma unroll
        for (int ct = 0; ct < 3; ++ct) acc[nf][ct] = (f32x4){0.f, 0.f, 0.f, 0.f};

    const f32x4 zf = (f32x4){0.f, 0.f, 0.f, 0.f};
    int arow0 = w * 32 + (lane & 15);
    int kq = (lane >> 4) * 8;
    int rb4 = w * 32 + ((lane >> 4) << 2);

    for (int ic = 0; ic < 8; ++ic) {
        __syncthreads();
#pragma unroll
        for (int p = 0; p < 10; ++p) {
            int q = p * 512 + tid;
            int cq = q % 10;
            int jj = (q / 10) & 63;
            int il = q / 640;
            const float4 v = *(const float4*)&W2[(((size_t)(ic * 8 + il) * 64 + jj) * CC) + cq * 4];
            Bc[il][cq * 4 + 0][jj] = __float2bfloat16(v.x);
            Bc[il][cq * 4 + 1][jj] = __float2bfloat16(v.y);
            Bc[il][cq * 4 + 2][jj] = __float2bfloat16(v.z);
            Bc[il][cq * 4 + 3][jj] = __float2bfloat16(v.w);
        }
        __syncthreads();

#pragma unroll
        for (int il = 0; il < 8; ++il) {
            int ii = ic * 8 + il;
            short8 a0k0 = *(const short8*)&hb[arow0][kq];
            short8 a0k1 = *(const short8*)&hb[arow0][32 + kq];
            short8 a1k0 = *(const short8*)&hb[arow0 + 16][kq];
            short8 a1k1 = *(const short8*)&hb[arow0 + 16][32 + kq];
            short8 b0k0 = *(const short8*)&Bc[il][(lane & 15)][kq];
            short8 b0k1 = *(const short8*)&Bc[il][(lane & 15)][32 + kq];
            short8 b1k0 = *(const short8*)&Bc[il][16 + (lane & 15)][kq];
            short8 b1k1 = *(const short8*)&Bc[il][16 + (lane & 15)][32 + kq];
            short8 b2k0 = *(const short8*)&Bc[il][32 + (lane & 15)][kq];
            short8 b2k1 = *(const short8*)&Bc[il][32 + (lane & 15)][32 + kq];
            float s0[4], s1[4];
#pragma unroll
            for (int r = 0; r < 4; ++r) {
                s0[r] = hf[rb4 + r][ii];
                s1[r] = hf[rb4 + 16 + r][ii];
            }
            f32x4 t;
            t = __builtin_amdgcn_mfma_f32_16x16x32_bf16(a0k0, b0k0, zf, 0, 0, 0);
            t = __builtin_amdgcn_mfma_f32_16x16x32_bf16(a0k1, b0k1, t, 0, 0, 0);
#pragma unroll
            for (int r = 0; r < 4; ++r) acc[0][0][r] = fmaf(s0[r], t[r], acc[0][0][r]);
            t = __builtin_amdgcn_mfma_f32_16x16x32_bf16(a0k0, b1k0, zf, 0, 0, 0);
            t = __builtin_amdgcn_mfma_f32_16x16x32_bf16(a0k1, b1k1, t, 0, 0, 0);
#pragma unroll
            for (int r = 0; r < 4; ++r) acc[0][1][r] = fmaf(s0[r], t[r], acc[0][1][r]);
            t = __builtin_amdgcn_mfma_f32_16x16x32_bf16(a0k0, b2k0, zf, 0, 0, 0);
            t = __builtin_amdgcn_mfma_f32_16x16x32_bf16(a0k1, b2k1, t, 0, 0, 0);
#pragma unroll
            for (int r = 0; r < 4; ++r) acc[0][2][r] = fmaf(s0[r], t[r], acc[0][2][r]);
            t = __builtin_amdgcn_mfma_f32_16x16x32_bf16(a1k0, b0k0, zf, 0, 0, 0);
            t = __builtin_amdgcn_mfma_f32_16x16x32_bf16(a1k1, b0k1, t, 0, 0, 0);
#pragma unroll
            for (int r = 0; r < 4; ++r) acc[1][0][r] = fmaf(s1[r], t[r], acc[1][0][r]);
            t = __builtin_amdgcn_mfma_f32_16x16x32_bf16(a1k0, b1k0, zf, 0, 0, 0);
            t = __builtin_amdgcn_mfma_f32_16x16x32_bf16(a1k1, b1k1, t, 0, 0, 0);
#pragma unroll
            for (int r = 0; r < 4; ++r) acc[1][1][r] = fmaf(s1[r], t[r], acc[1][1][r]);
            t = __builtin_amdgcn_mfma_f32_16x16x32_bf16(a1k0, b2k0, zf, 0, 0, 0);
            t = __builtin_amdgcn_mfma_f32_16x16x32_bf16(a1k1, b2k1, t, 0, 0, 0);
#pragma unroll
            for (int r = 0; r < 4; ++r) acc[1][2][r] = fmaf(s1[r], t[r], acc[1][2][r]);
        }
    }

#pragma unroll
    for (int nf = 0; nf < 2; ++nf) {
#pragma unroll
        for (int ct = 0; ct < 3; ++ct) {
            int c = ct * 16 + (lane & 15);
            if (c < CC) {
                float bias = b2[c];
#pragma unroll
                for (int r = 0; r < 4; ++r) {
                    int node = nbase + w * 32 + nf * 16 + ((lane >> 4) << 2) + r;
                    if (node < NN) out[(size_t)node * CC + c] = acc[nf][ct][r] + bias;
                }
            }
        }
    }
}

// ---------------- log_softmax in place, wave per node ----------------
__global__ void k_lsm(float* __restrict__ out) {
    int lane = threadIdx.x & 63;
    int n = (blockIdx.x * 256 + threadIdx.x) >> 6;
    if (n >= NN) return;
    float x = (lane < CC) ? out[(size_t)n * CC + lane] : -INFINITY;
    float m = x;
    for (int off = 32; off; off >>= 1) m = fmaxf(m, __shfl_xor(m, off));
    float e = (lane < CC) ? expf(x - m) : 0.f;
    float s = e;
    for (int off = 32; off; off >>= 1) s += __shfl_xor(s, off);
    float lse = m + logf(s);
    if (lane < CC) out[(size_t)n * CC + lane] = x - lse;
}

extern "C" void kernel_launch(void* const* d_in, const int* in_sizes, int n_in,
                              void* d_out, int out_size, void* d_ws, size_t ws_size,
                              hipStream_t stream) {
    const float* x  = (const float*)d_in[0];
    const int*   ei = (const int*)d_in[1];
    const float* ew = (const float*)d_in[2];
    const float* W0 = (const float*)d_in[3];
    const float* b0 = (const float*)d_in[4];
    const float* Wl = (const float*)d_in[5];
    const float* W2 = (const float*)d_in[6];
    const float* b2 = (const float*)d_in[7];
    float* out = (float*)d_out;

    char* ws = (char*)d_ws;
    size_t off = 0;
    auto alloc = [&](size_t b) { size_t o = off; off += (b + 255) & ~(size_t)255; return o; };
    float* h0   = (float*)(ws + alloc((size_t)NN * HH * 4));
    float* hA   = (float*)(ws + alloc((size_t)NN * HH * 4));
    float* hB   = (float*)(ws + alloc((size_t)NN * HH * 4));
    int*   cnt  = (int*)(ws + alloc((size_t)VN * 4));
    int*   incl = (int*)(ws + alloc((size_t)VN * 4));
    int*   bsum = (int*)(ws + alloc(1024));
    int*   row4 = (int*)(ws + alloc((size_t)(VN + 1) * 4));
    int*   bcur = (int*)(ws + alloc((size_t)NBK * 4));
    int2*  payA = (int2*)(ws + alloc((size_t)EE * 8));
    int2*  payB = (int2*)(ws + alloc((size_t)EE * 8));

    const int* srcp = ei;
    const int* dstp = ei + EE;

    hipMemsetAsync(cnt, 0, (size_t)VN * 4, stream);
    k_hist4<<<(EE + 255) / 256, 256, 0, stream>>>(srcp, dstp, cnt);
    k_scanA<<<196, 1024, 0, stream>>>(cnt, incl, bsum);
    k_scanB2<<<1, 1024, 0, stream>>>(bsum);
    k_scanC<<<196, 1024, 0, stream>>>(cnt, incl, bsum, row4);
    k_binit<<<(NBK + 255) / 256, 256, 0, stream>>>(row4, bcur);
    k_scatA<<<(EE + 255) / 256, 256, 0, stream>>>(srcp, dstp, ew, bcur, payA);
    k_scatB<<<NBK, 256, 0, stream>>>(row4, payA, payB);

    k_h0m<<<196, 512, 0, stream>>>(x, W0, b0, h0);

    const float* hin = h0;
    float* ho = hA;
    for (int l = 0; l < LL; l++) {
        float beta = (float)log(0.5 / (double)(l + 1) + 1.0);
        k_layer<<<3125, 256, 0, stream>>>(hin, h0, row4, payB,
                                          Wl + (size_t)l * HH * HH, beta, ho);
        hin = ho;
        ho = (ho == hA) ? hB : hA;
    }

    k_head<<<196, 512, 0, stream>>>(hin, W2, b2, out);
    k_lsm<<<(NN * 64 + 255) / 256, 256, 0, stream>>>(out);
}

// Round 6
// 644.550 us; speedup vs baseline: 1.6757x; 1.6757x over previous
//
#include <hip/hip_runtime.h>
#include <hip/hip_bf16.h>
#include <math.h>

#define NN 50000
#define FF 256
#define HH 64
#define LL 8
#define EE 1600000
#define CC 40

using short8 = __attribute__((ext_vector_type(8))) short;
using f32x4  = __attribute__((ext_vector_type(4))) float;

static __device__ __forceinline__ unsigned short f2b(float f) {
    union { __hip_bfloat16 h; unsigned short u; } cv;
    cv.h = __float2bfloat16(f);
    return cv.u;
}
static __device__ __forceinline__ float b2f(unsigned short u) {
    return __uint_as_float((unsigned)u << 16);
}

// ---------------- CSR build ----------------

__global__ void k_hist(const int* __restrict__ dst, int* __restrict__ cnt) {
    int e = blockIdx.x * 256 + threadIdx.x;
    if (e < EE) atomicAdd(&cnt[dst[e]], 1);
}

__global__ void k_scanA(const int* __restrict__ cnt, int* __restrict__ incl, int* __restrict__ bsum) {
    __shared__ int buf[1024];
    int i = blockIdx.x * 1024 + threadIdx.x;
    int v = (i < NN) ? cnt[i] : 0;
    buf[threadIdx.x] = v;
    __syncthreads();
    for (int off = 1; off < 1024; off <<= 1) {
        int t = (threadIdx.x >= off) ? buf[threadIdx.x - off] : 0;
        __syncthreads();
        buf[threadIdx.x] += t;
        __syncthreads();
    }
    if (i < NN) incl[i] = buf[threadIdx.x];
    if (threadIdx.x == 1023) bsum[blockIdx.x] = buf[1023];
}

__global__ void k_scanB(int* __restrict__ bsum) {
    int t = threadIdx.x;
    int vin = (t < 49) ? bsum[t] : 0;
    int v = vin;
    for (int off = 1; off < 64; off <<= 1) {
        int u = __shfl_up(v, off);
        if (t >= off) v += u;
    }
    if (t < 49) bsum[t] = v - vin;  // exclusive
}

__global__ void k_scanC(const int* __restrict__ cnt, const int* __restrict__ incl,
                        const int* __restrict__ bsum, int* __restrict__ row_ptr,
                        int* __restrict__ cursor) {
    int i = blockIdx.x * 1024 + threadIdx.x;
    if (i < NN) {
        int e = incl[i] - cnt[i] + bsum[blockIdx.x];
        row_ptr[i] = e;
        cursor[i] = e;
    }
    if (i == 0) row_ptr[NN] = EE;
}

// pay word: src (16 high bits) | bf16(w) (16 low bits)
__global__ void k_scatter(const int* __restrict__ src, const int* __restrict__ dst,
                          const float* __restrict__ w, int* __restrict__ cursor,
                          unsigned* __restrict__ pay) {
    int e = blockIdx.x * 256 + threadIdx.x;
    if (e < EE) {
        int d = dst[e];
        int p = atomicAdd(&cursor[d], 1);
        pay[p] = ((unsigned)src[e] << 16) | (unsigned)f2b(w[e]);
    }
}

// ---------------- initial projection via MFMA: h0 = relu(x @ W0 + b0) ----------------
// writes h0f (fp32, for per-layer residual blend) and h0b (bf16, layer-1 gather src)
__global__ __launch_bounds__(512) void k_h0m(const float* __restrict__ x,
                                             const float* __restrict__ W0,
                                             const float* __restrict__ b0,
                                             float* __restrict__ h0f,
                                             unsigned short* __restrict__ h0b) {
    __shared__ __align__(16) __hip_bfloat16 ax[256][72];
    __shared__ __align__(16) __hip_bfloat16 bw[64][72];

    int tid = threadIdx.x;
    int lane = tid & 63;
    int w = tid >> 6;
    int nbase = blockIdx.x * 256;

    f32x4 acc[2][4];
#pragma unroll
    for (int nf = 0; nf < 2; ++nf)
#pragma unroll
        for (int cf = 0; cf < 4; ++cf) acc[nf][cf] = (f32x4){0.f, 0.f, 0.f, 0.f};

    int arow = w * 32 + (lane & 15);
    int kq = (lane >> 4) * 8;

    for (int kc = 0; kc < 4; ++kc) {
        __syncthreads();
#pragma unroll
        for (int p = 0; p < 8; ++p) {
            int q = p * 512 + tid;
            int r = q >> 4, cq = q & 15;
            int node = nbase + r;
            float4 v = {0.f, 0.f, 0.f, 0.f};
            if (node < NN) v = *(const float4*)&x[(size_t)node * FF + kc * 64 + cq * 4];
            __hip_bfloat16* d = &ax[r][cq * 4];
            d[0] = __float2bfloat16(v.x);
            d[1] = __float2bfloat16(v.y);
            d[2] = __float2bfloat16(v.z);
            d[3] = __float2bfloat16(v.w);
        }
#pragma unroll
        for (int u = 0; u < 8; ++u) {
            int k = (tid >> 6) * 8 + u;
            float v = W0[(size_t)(kc * 64 + k) * HH + lane];
            bw[lane][k] = __float2bfloat16(v);
        }
        __syncthreads();
#pragma unroll
        for (int ks = 0; ks < 2; ++ks) {
            short8 a0 = *(const short8*)&ax[arow][ks * 32 + kq];
            short8 a1 = *(const short8*)&ax[arow + 16][ks * 32 + kq];
#pragma unroll
            for (int cf = 0; cf < 4; ++cf) {
                short8 b = *(const short8*)&bw[cf * 16 + (lane & 15)][ks * 32 + kq];
                acc[0][cf] = __builtin_amdgcn_mfma_f32_16x16x32_bf16(a0, b, acc[0][cf], 0, 0, 0);
                acc[1][cf] = __builtin_amdgcn_mfma_f32_16x16x32_bf16(a1, b, acc[1][cf], 0, 0, 0);
            }
        }
    }

#pragma unroll
    for (int nf = 0; nf < 2; ++nf) {
#pragma unroll
        for (int cf = 0; cf < 4; ++cf) {
            int c = cf * 16 + (lane & 15);
            float bias = b0[c];
#pragma unroll
            for (int r = 0; r < 4; ++r) {
                int node = nbase + w * 32 + nf * 16 + ((lane >> 4) << 2) + r;
                if (node < NN) {
                    float v = fmaxf(acc[nf][cf][r] + bias, 0.f);
                    h0f[(size_t)node * HH + c] = v;
                    h0b[(size_t)node * HH + c] = f2b(v);
                }
            }
        }
    }
}

// ---------------- fused layer: SpMM(bf16 gather) + blend + matvec + relu ----------------
// one wave per 4 nodes; lane = feature channel.
__global__ void k_layer(const unsigned short* __restrict__ hin, const float* __restrict__ h0,
                        const int* __restrict__ row_ptr, const unsigned* __restrict__ pay,
                        const float* __restrict__ Wl, float beta,
                        unsigned short* __restrict__ hout) {
    int lane = threadIdx.x & 63;
    int n0 = (blockIdx.x * 4 + (threadIdx.x >> 6)) * 4;

    float hmix[4];
#pragma unroll
    for (int u = 0; u < 4; ++u) {
        int n = n0 + u;
        int rb = row_ptr[n], re = row_ptr[n + 1];
        float acc = 0.f;
        for (int base = rb; base < re; base += 64) {
            int idx = base + lane;
            unsigned pv = (idx < re) ? pay[idx] : 0u;
            int ecnt = min(64, re - base);
            int k = 0;
            for (; k + 16 <= ecnt; k += 16) {
                float vv[16], ws[16];
#pragma unroll
                for (int t = 0; t < 16; t++) {
                    unsigned pk = (unsigned)__builtin_amdgcn_readlane((int)pv, k + t);
                    ws[t] = __uint_as_float((pk & 0xFFFFu) << 16);
                    vv[t] = b2f(hin[(size_t)(pk >> 16) * HH + lane]);
                }
#pragma unroll
                for (int t = 0; t < 16; t++) acc = fmaf(ws[t], vv[t], acc);
            }
            if (k + 8 <= ecnt) {
                float vv[8], ws[8];
#pragma unroll
                for (int t = 0; t < 8; t++) {
                    unsigned pk = (unsigned)__builtin_amdgcn_readlane((int)pv, k + t);
                    ws[t] = __uint_as_float((pk & 0xFFFFu) << 16);
                    vv[t] = b2f(hin[(size_t)(pk >> 16) * HH + lane]);
                }
#pragma unroll
                for (int t = 0; t < 8; t++) acc = fmaf(ws[t], vv[t], acc);
                k += 8;
            }
            for (; k < ecnt; k++) {
                unsigned pk = (unsigned)__builtin_amdgcn_readlane((int)pv, k);
                float ww = __uint_as_float((pk & 0xFFFFu) << 16);
                acc = fmaf(ww, b2f(hin[(size_t)(pk >> 16) * HH + lane]), acc);
            }
        }
        hmix[u] = fmaf(0.9f, acc, 0.1f * h0[(size_t)n * HH + lane]);
    }

    int hb[4];
#pragma unroll
    for (int u = 0; u < 4; ++u) hb[u] = __float_as_int(hmix[u]);
    float a2[4] = {0.f, 0.f, 0.f, 0.f};
#pragma unroll
    for (int j = 0; j < HH; j++) {
        float wr = Wl[j * HH + lane];
#pragma unroll
        for (int u = 0; u < 4; ++u) {
            float hj = __int_as_float(__builtin_amdgcn_readlane(hb[u], j));
            a2[u] = fmaf(hj, wr, a2[u]);
        }
    }
#pragma unroll
    for (int u = 0; u < 4; ++u) {
        float outv = (1.f - beta) * hmix[u] + beta * a2[u];
        hout[(size_t)(n0 + u) * HH + lane] = f2b(fmaxf(outv, 0.f));
    }
}

// ---------------- head via MFMA (h input is bf16) ----------------
__global__ __launch_bounds__(512) void k_head(const unsigned short* __restrict__ h,
                                              const float* __restrict__ W2,
                                              const float* __restrict__ b2,
                                              float* __restrict__ out) {
    __shared__ __align__(16) unsigned short hb[256][72];
    __shared__ float hf[256][65];
    __shared__ __align__(16) __hip_bfloat16 Bc[8][48][72];

    int tid = threadIdx.x;
    int lane = tid & 63;
    int w = tid >> 6;
    int nbase = blockIdx.x * 256;

#pragma unroll
    for (int p = 0; p < 32; ++p) {
        int idx = p * 512 + tid;
        int r = idx >> 6, c = idx & 63;
        int node = nbase + r;
        unsigned short raw = (node < NN) ? h[(size_t)node * HH + c] : 0;
        hf[r][c] = b2f(raw);
        hb[r][c] = raw;
    }
    for (int p = tid; p < 8 * 8 * 64; p += 512) {
        int il = p >> 9;
        int c = 40 + ((p >> 6) & 7);
        int j = p & 63;
        Bc[il][c][j] = __float2bfloat16(0.f);
    }

    f32x4 acc[2][3];
#pragma unroll
    for (int nf = 0; nf < 2; ++nf)
#pragma unroll
        for (int ct = 0; ct < 3; ++ct) acc[nf][ct] = (f32x4){0.f, 0.f, 0.f, 0.f};

    const f32x4 zf = (f32x4){0.f, 0.f, 0.f, 0.f};
    int arow0 = w * 32 + (lane & 15);
    int kq = (lane >> 4) * 8;
    int rb4 = w * 32 + ((lane >> 4) << 2);

    for (int ic = 0; ic < 8; ++ic) {
        __syncthreads();
#pragma unroll
        for (int p = 0; p < 10; ++p) {
            int q = p * 512 + tid;
            int cq = q % 10;
            int jj = (q / 10) & 63;
            int il = q / 640;
            const float4 v = *(const float4*)&W2[(((size_t)(ic * 8 + il) * 64 + jj) * CC) + cq * 4];
            Bc[il][cq * 4 + 0][jj] = __float2bfloat16(v.x);
            Bc[il][cq * 4 + 1][jj] = __float2bfloat16(v.y);
            Bc[il][cq * 4 + 2][jj] = __float2bfloat16(v.z);
            Bc[il][cq * 4 + 3][jj] = __float2bfloat16(v.w);
        }
        __syncthreads();

#pragma unroll
        for (int il = 0; il < 8; ++il) {
            int ii = ic * 8 + il;
            short8 a0k0 = *(const short8*)&hb[arow0][kq];
            short8 a0k1 = *(const short8*)&hb[arow0][32 + kq];
            short8 a1k0 = *(const short8*)&hb[arow0 + 16][kq];
            short8 a1k1 = *(const short8*)&hb[arow0 + 16][32 + kq];
            short8 b0k0 = *(const short8*)&Bc[il][(lane & 15)][kq];
            short8 b0k1 = *(const short8*)&Bc[il][(lane & 15)][32 + kq];
            short8 b1k0 = *(const short8*)&Bc[il][16 + (lane & 15)][kq];
            short8 b1k1 = *(const short8*)&Bc[il][16 + (lane & 15)][32 + kq];
            short8 b2k0 = *(const short8*)&Bc[il][32 + (lane & 15)][kq];
            short8 b2k1 = *(const short8*)&Bc[il][32 + (lane & 15)][32 + kq];
            float s0[4], s1[4];
#pragma unroll
            for (int r = 0; r < 4; ++r) {
                s0[r] = hf[rb4 + r][ii];
                s1[r] = hf[rb4 + 16 + r][ii];
            }
            f32x4 t;
            t = __builtin_amdgcn_mfma_f32_16x16x32_bf16(a0k0, b0k0, zf, 0, 0, 0);
            t = __builtin_amdgcn_mfma_f32_16x16x32_bf16(a0k1, b0k1, t, 0, 0, 0);
#pragma unroll
            for (int r = 0; r < 4; ++r) acc[0][0][r] = fmaf(s0[r], t[r], acc[0][0][r]);
            t = __builtin_amdgcn_mfma_f32_16x16x32_bf16(a0k0, b1k0, zf, 0, 0, 0);
            t = __builtin_amdgcn_mfma_f32_16x16x32_bf16(a0k1, b1k1, t, 0, 0, 0);
#pragma unroll
            for (int r = 0; r < 4; ++r) acc[0][1][r] = fmaf(s0[r], t[r], acc[0][1][r]);
            t = __builtin_amdgcn_mfma_f32_16x16x32_bf16(a0k0, b2k0, zf, 0, 0, 0);
            t = __builtin_amdgcn_mfma_f32_16x16x32_bf16(a0k1, b2k1, t, 0, 0, 0);
#pragma unroll
            for (int r = 0; r < 4; ++r) acc[0][2][r] = fmaf(s0[r], t[r], acc[0][2][r]);
            t = __builtin_amdgcn_mfma_f32_16x16x32_bf16(a1k0, b0k0, zf, 0, 0, 0);
            t = __builtin_amdgcn_mfma_f32_16x16x32_bf16(a1k1, b0k1, t, 0, 0, 0);
#pragma unroll
            for (int r = 0; r < 4; ++r) acc[1][0][r] = fmaf(s1[r], t[r], acc[1][0][r]);
            t = __builtin_amdgcn_mfma_f32_16x16x32_bf16(a1k0, b1k0, zf, 0, 0, 0);
            t = __builtin_amdgcn_mfma_f32_16x16x32_bf16(a1k1, b1k1, t, 0, 0, 0);
#pragma unroll
            for (int r = 0; r < 4; ++r) acc[1][1][r] = fmaf(s1[r], t[r], acc[1][1][r]);
            t = __builtin_amdgcn_mfma_f32_16x16x32_bf16(a1k0, b2k0, zf, 0, 0, 0);
            t = __builtin_amdgcn_mfma_f32_16x16x32_bf16(a1k1, b2k1, t, 0, 0, 0);
#pragma unroll
            for (int r = 0; r < 4; ++r) acc[1][2][r] = fmaf(s1[r], t[r], acc[1][2][r]);
        }
    }

#pragma unroll
    for (int nf = 0; nf < 2; ++nf) {
#pragma unroll
        for (int ct = 0; ct < 3; ++ct) {
            int c = ct * 16 + (lane & 15);
            if (c < CC) {
                float bias = b2[c];
#pragma unroll
                for (int r = 0; r < 4; ++r) {
                    int node = nbase + w * 32 + nf * 16 + ((lane >> 4) << 2) + r;
                    if (node < NN) out[(size_t)node * CC + c] = acc[nf][ct][r] + bias;
                }
            }
        }
    }
}

// ---------------- log_softmax in place, wave per node ----------------
__global__ void k_lsm(float* __restrict__ out) {
    int lane = threadIdx.x & 63;
    int n = (blockIdx.x * 256 + threadIdx.x) >> 6;
    if (n >= NN) return;
    float x = (lane < CC) ? out[(size_t)n * CC + lane] : -INFINITY;
    float m = x;
    for (int off = 32; off; off >>= 1) m = fmaxf(m, __shfl_xor(m, off));
    float e = (lane < CC) ? expf(x - m) : 0.f;
    float s = e;
    for (int off = 32; off; off >>= 1) s += __shfl_xor(s, off);
    float lse = m + logf(s);
    if (lane < CC) out[(size_t)n * CC + lane] = x - lse;
}

extern "C" void kernel_launch(void* const* d_in, const int* in_sizes, int n_in,
                              void* d_out, int out_size, void* d_ws, size_t ws_size,
                              hipStream_t stream) {
    const float* x  = (const float*)d_in[0];
    const int*   ei = (const int*)d_in[1];
    const float* ew = (const float*)d_in[2];
    const float* W0 = (const float*)d_in[3];
    const float* b0 = (const float*)d_in[4];
    const float* Wl = (const float*)d_in[5];
    const float* W2 = (const float*)d_in[6];
    const float* b2 = (const float*)d_in[7];
    float* out = (float*)d_out;

    char* ws = (char*)d_ws;
    size_t off = 0;
    auto alloc = [&](size_t b) { size_t o = off; off += (b + 255) & ~(size_t)255; return o; };
    float*          h0f = (float*)(ws + alloc((size_t)NN * HH * 4));
    unsigned short* h0b = (unsigned short*)(ws + alloc((size_t)NN * HH * 2));
    unsigned short* hA  = (unsigned short*)(ws + alloc((size_t)NN * HH * 2));
    unsigned short* hB  = (unsigned short*)(ws + alloc((size_t)NN * HH * 2));
    int*      cnt     = (int*)(ws + alloc((size_t)NN * 4));
    int*      incl    = (int*)(ws + alloc((size_t)NN * 4));
    int*      bsum    = (int*)(ws + alloc(256));
    int*      row_ptr = (int*)(ws + alloc((size_t)(NN + 1) * 4));
    int*      cursor  = (int*)(ws + alloc((size_t)NN * 4));
    unsigned* pay     = (unsigned*)(ws + alloc((size_t)EE * 4));

    const int* srcp = ei;
    const int* dstp = ei + EE;

    hipMemsetAsync(cnt, 0, (size_t)NN * 4, stream);
    k_hist<<<(EE + 255) / 256, 256, 0, stream>>>(dstp, cnt);
    k_scanA<<<49, 1024, 0, stream>>>(cnt, incl, bsum);
    k_scanB<<<1, 64, 0, stream>>>(bsum);
    k_scanC<<<49, 1024, 0, stream>>>(cnt, incl, bsum, row_ptr, cursor);
    k_scatter<<<(EE + 255) / 256, 256, 0, stream>>>(srcp, dstp, ew, cursor, pay);

    k_h0m<<<196, 512, 0, stream>>>(x, W0, b0, h0f, h0b);

    const unsigned short* hin = h0b;
    unsigned short* ho = hA;
    for (int l = 0; l < LL; l++) {
        float beta = (float)log(0.5 / (double)(l + 1) + 1.0);
        k_layer<<<3125, 256, 0, stream>>>(hin, h0f, row_ptr, pay,
                                          Wl + (size_t)l * HH * HH, beta, ho);
        hin = ho;
        ho = (ho == hA) ? hB : hA;
    }

    k_head<<<196, 512, 0, stream>>>(hin, W2, b2, out);
    k_lsm<<<(NN * 64 + 255) / 256, 256, 0, stream>>>(out);
}